// Round 11
// baseline (667.680 us; speedup 1.0000x reference)
//
#include <hip/hip_runtime.h>
#include <cstdint>
#include <cstddef>

#define HIDDIM 128
#define NGRAPH_MAX 512
#define LDSPAD 136   // 128 + 8 bf16 pad: row stride 272B (16B-aligned, bank-conflict-free frag reads)
#define NBKT_MAX 512 // coarse buckets of 256 nodes (dst>>8); N<=131072

// Feature matrices (x0/x1/x2/y/s) are stored SLICE-MAJOR:
//   slice = col/16 (8 slices), layout[slice][node][16 cols bf16]
// so that k_aggc block (dgrp, slice=blockIdx%8) touches a 3.2MB/XCD-L2-resident
// footprint (r9: row-major random gather refetches full 25.6MB per XCD -> 193MB HBM).

using short8 = __attribute__((ext_vector_type(8))) short;
using f32x4  = __attribute__((ext_vector_type(4))) float;

__device__ __forceinline__ unsigned short f2bf(float x) {
    union { float f; uint32_t u; } v; v.f = x;
    uint32_t r = v.u + 0x7fffu + ((v.u >> 16) & 1u);   // RNE
    return (unsigned short)(r >> 16);
}
__device__ __forceinline__ uint32_t pack2(float a, float b) {
    return (uint32_t)f2bf(a) | ((uint32_t)f2bf(b) << 16);
}
__device__ __forceinline__ float bflo(uint32_t u) { return __uint_as_float(u << 16); }
__device__ __forceinline__ float bfhi(uint32_t u) { return __uint_as_float(u & 0xffff0000u); }

// ---------------------------------------------------------------- fused prep: feat | bcount | nodestats | wt
__global__ void k_prep(const int* __restrict__ nt, const int* __restrict__ ih,
                       const float* __restrict__ flags, const int* __restrict__ depth,
                       const float* __restrict__ embN, const float* __restrict__ embI,
                       const int* __restrict__ edst, const int* __restrict__ batch,
                       const float* __restrict__ Wn0, const float* __restrict__ Ws0,
                       const float* __restrict__ Wn1, const float* __restrict__ Ws1,
                       int K0, int N, int E, int G,
                       uint4* __restrict__ x0s, unsigned short* __restrict__ Wt,
                       int* __restrict__ bcount, int* __restrict__ counts,
                       int* __restrict__ maxd,
                       int nbF, int nbC, int nbN) {
    __shared__ int hist[NBKT_MAX];
    __shared__ int red[256];
    int b = blockIdx.x, t = threadIdx.x;
    if (b < nbF) {
        // ---- node features: 16 threads/node, one uint4 (8 bf16 cols) each, slice-major store
        int idx = b * 256 + t;
        int i = idx >> 4;
        int seg = idx & 15;
        if (i >= N) return;
        uint4 o = make_uint4(0u, 0u, 0u, 0u);
        if (seg < 8) {
            const float4* r = (const float4*)(embN + (size_t)nt[i] * 64 + seg * 8);
            float4 v0 = r[0], v1 = r[1];
            o.x = pack2(v0.x, v0.y); o.y = pack2(v0.z, v0.w);
            o.z = pack2(v1.x, v1.y); o.w = pack2(v1.z, v1.w);
        } else if (seg < 12) {
            const float4* r = (const float4*)(embI + (size_t)ih[i] * 32 + (seg - 8) * 8);
            float4 v0 = r[0], v1 = r[1];
            o.x = pack2(v0.x, v0.y); o.y = pack2(v0.z, v0.w);
            o.z = pack2(v1.x, v1.y); o.w = pack2(v1.z, v1.w);
        } else if (seg == 12) {
            const float* fp = flags + (size_t)i * 5;
            o.x = pack2(fp[0], fp[1]);
            o.y = pack2(fp[2], fp[3]);
            o.z = pack2(fp[4], 0.f);   // col101 (depth) written by k_scan2x
        }
        // slice-major: slice = seg>>1, h = seg&1
        x0s[(size_t)(seg >> 1) * (N * 2) + (size_t)i * 2 + (seg & 1)] = o;
    } else if (b < nbF + nbC) {
        hist[t] = 0; hist[t + 256] = 0;
        __syncthreads();
        int c0 = (b - nbF) * 4096;
        int ce = min(4096, E - c0);
        for (int i = t; i < ce; i += 256)
            atomicAdd(&hist[edst[c0 + i] >> 8], 1);
        __syncthreads();
        for (int bb = t; bb < NBKT_MAX; bb += 256)
            if (hist[bb]) atomicAdd(&bcount[bb], hist[bb]);
    } else if (b < nbF + nbC + nbN) {
        for (int g = t; g < G; g += 256) hist[g] = 0;
        __syncthreads();
        int i = (b - nbF - nbC) * 256 + t;
        int d = 0;
        if (i < N) {
            atomicAdd(&hist[batch[i]], 1);
            d = depth[i];
        }
        red[t] = d;
        __syncthreads();
        for (int off = 128; off > 0; off >>= 1) {
            if (t < off) red[t] = max(red[t], red[t + off]);
            __syncthreads();
        }
        if (t == 0) atomicMax(maxd, red[0]);
        for (int g = t; g < G; g += 256)
            if (hist[g]) atomicAdd(&counts[g], hist[g]);
    } else {
        int idx = (b - nbF - nbC - nbN) * 256 + t;   // 65536 total
        int mat = idx >> 14;
        int rem = idx & 16383;
        int n = rem >> 7, k = rem & 127;
        const float* W = (mat == 0) ? Wn0 : (mat == 1) ? Ws0 : (mat == 2) ? Wn1 : Ws1;
        int K = (mat < 2) ? K0 : HIDDIM;
        Wt[(size_t)mat * HIDDIM * HIDDIM + n * HIDDIM + k] =
            (k < K) ? f2bf(W[(size_t)k * HIDDIM + n]) : (unsigned short)0;
    }
}

// ---------------------------------------------------------------- fused scans + depth column (512 thr)
__global__ void k_scan2x(const int* __restrict__ bcount, int* __restrict__ boff,
                         int* __restrict__ bcur, int* __restrict__ rowptr,
                         const int* __restrict__ counts, int* __restrict__ gstart,
                         const int* __restrict__ depth, const int* __restrict__ maxd,
                         unsigned short* __restrict__ x0s,
                         int nbkt, int N, int E, int G) {
    __shared__ int sd[512];
    int b = blockIdx.x, t = threadIdx.x;
    if (b == 0) {
        int v = (t < nbkt) ? bcount[t] : 0;
        sd[t] = v;
        __syncthreads();
        for (int off = 1; off < 512; off <<= 1) {
            int x = (t >= off) ? sd[t - off] : 0;
            __syncthreads();
            sd[t] += x;
            __syncthreads();
        }
        if (t < nbkt) { boff[t] = sd[t] - v; bcur[t] = sd[t] - v; }
        if (t == 0) { boff[nbkt] = E; rowptr[N] = E; }
    } else if (b == 1) {
        int v = (t < G) ? counts[t] : 0;
        sd[t] = v;
        __syncthreads();
        for (int off = 1; off < 512; off <<= 1) {
            int x = (t >= off) ? sd[t - off] : 0;
            __syncthreads();
            sd[t] += x;
            __syncthreads();
        }
        if (t < G) gstart[t] = sd[t] - v;
        if (t == G - 1) gstart[G] = sd[t];
    } else {
        int i = (b - 2) * 512 + t;
        if (i < N) {
            float md = fmaxf((float)(*maxd), 1.0f);
            // col 101 -> slice 6, within-slice col 5
            x0s[(size_t)6 * N * 16 + (size_t)i * 16 + 5] = f2bf((float)depth[i] / md);
        }
    }
}

// ---------------------------------------------------------------- bucket scatter (unchanged)
__global__ void k_bscatter(const int* __restrict__ src, const int* __restrict__ dst,
                           int* __restrict__ bcur, int2* __restrict__ ebuf, int E, int nbkt) {
    __shared__ int2 stage[4096];        // 32 KB
    __shared__ int hist[NBKT_MAX];
    __shared__ int ofs[NBKT_MAX];
    __shared__ int cur[NBKT_MAX];
    __shared__ int gbase[NBKT_MAX];
    __shared__ int scanbuf[256];
    int t = threadIdx.x;
    int c0 = blockIdx.x * 4096;
    int ce = min(4096, E - c0);

    hist[t] = 0; hist[t + 256] = 0;
    __syncthreads();
    for (int i = t; i < ce; i += 256)
        atomicAdd(&hist[dst[c0 + i] >> 8], 1);
    __syncthreads();
    int h2a = hist[2 * t], h2b = hist[2 * t + 1];
    int ps = h2a + h2b;
    scanbuf[t] = ps;
    __syncthreads();
    for (int off = 1; off < 256; off <<= 1) {
        int x = (t >= off) ? scanbuf[t - off] : 0;
        __syncthreads();
        scanbuf[t] += x;
        __syncthreads();
    }
    int ex = scanbuf[t] - ps;
    ofs[2 * t] = ex;           cur[2 * t] = ex;
    ofs[2 * t + 1] = ex + h2a; cur[2 * t + 1] = ex + h2a;
    __syncthreads();
    for (int i = t; i < ce; i += 256) {
        int d = dst[c0 + i];
        int p = atomicAdd(&cur[d >> 8], 1);
        stage[p] = make_int2(src[c0 + i], d);
    }
    __syncthreads();
    for (int b = t; b < nbkt; b += 256) {
        int c = hist[b];
        gbase[b] = c ? atomicAdd(&bcur[b], c) : 0;
    }
    __syncthreads();
    for (int j = t; j < ce; j += 256) {
        int2 p = stage[j];
        int b = p.y >> 8;
        ebuf[gbase[b] + (j - ofs[b])] = p;
    }
}

// ---------------------------------------------------------------- per-bucket CSR build (unchanged)
__global__ void k_build(const int2* __restrict__ ebuf, const int* __restrict__ boff,
                        int* __restrict__ rowptr, float* __restrict__ invd,
                        int* __restrict__ srcs, int N) {
    __shared__ int ldeg[256];
    __shared__ int lofs[256];
    __shared__ int lcur[256];
    int b = blockIdx.x, t = threadIdx.x;
    int n0 = b << 8;
    int s = boff[b], e = boff[b + 1];
    ldeg[t] = 0;
    __syncthreads();
    for (int i = s + t; i < e; i += 256)
        atomicAdd(&ldeg[ebuf[i].y & 255], 1);
    __syncthreads();
    int v = ldeg[t];
    lofs[t] = v;
    __syncthreads();
    for (int off = 1; off < 256; off <<= 1) {
        int x = (t >= off) ? lofs[t - off] : 0;
        __syncthreads();
        lofs[t] += x;
        __syncthreads();
    }
    int excl = lofs[t] - v;
    int node = n0 + t;
    if (node < N) {
        rowptr[node] = s + excl;
        invd[node] = 1.0f / (float)max(v, 1);
    }
    lcur[t] = excl;
    __syncthreads();
    for (int i = s + t; i < e; i += 256) {
        int2 p = ebuf[i];
        int slot = atomicAdd(&lcur[p.y & 255], 1);
        srcs[s + slot] = p.x;
    }
}

// ---------------------------------------------------------------- dual bf16 MFMA GEMM (K=128 fixed), slice-major I/O
// Y = X @ Wn ; S = X @ Ws + bias_s + bias_n  (bf16, fp32 acc). B in LDS (r7 lesson),
// A hoisted from global (coalesced in slice-major: quad pair covers 32B/node),
// epilogue LDS round-trip -> coalesced 16B slice-major stores.
__global__ __launch_bounds__(256, 2) void k_gemm2(
    const uint4* __restrict__ Xs,
    const unsigned short* __restrict__ Wtn, const unsigned short* __restrict__ Wts,
    int N, const float* __restrict__ bias_s, const float* __restrict__ bias_n,
    uint4* __restrict__ Ys, uint4* __restrict__ Ss) {
    __shared__ unsigned short Bn[128 * LDSPAD];   // 34.8 KB
    __shared__ unsigned short Bs[128 * LDSPAD];   // 34.8 KB
    int t = threadIdx.x;
    int rowBase = blockIdx.x << 7;
    const size_t N2 = (size_t)N * 2;

    #pragma unroll
    for (int it = 0; it < 8; it++) {
        int idx = t + it * 256;
        int n = idx >> 4, seg = idx & 15;
        *(uint4*)&Bn[n * LDSPAD + seg * 8] = *(const uint4*)(Wtn + n * HIDDIM + seg * 8);
        *(uint4*)&Bs[n * LDSPAD + seg * 8] = *(const uint4*)(Wts + n * HIDDIM + seg * 8);
    }

    int lane = t & 63;
    int wv = t >> 6;
    int ml = lane & 15;
    int quad = lane >> 4;
    int m0 = wv * 32;

    // hoisted A-frags; col group kt*32+quad*8 -> slice 2kt+(quad>>1), h=quad&1
    int gr0 = rowBase + m0 + ml;
    int gr1 = gr0 + 16;
    uint4 af0[4], af1[4];
    #pragma unroll
    for (int kt = 0; kt < 4; kt++) {
        uint4 z = make_uint4(0u, 0u, 0u, 0u);
        size_t sb = (size_t)(2 * kt + (quad >> 1)) * N2 + (quad & 1);
        af0[kt] = (gr0 < N) ? Xs[sb + (size_t)gr0 * 2] : z;
        af1[kt] = (gr1 < N) ? Xs[sb + (size_t)gr1 * 2] : z;
    }
    __syncthreads();

    f32x4 accY[2][8], accS[2][8];
    #pragma unroll
    for (int i = 0; i < 2; i++)
        #pragma unroll
        for (int j = 0; j < 8; j++) {
            accY[i][j] = (f32x4){0.f, 0.f, 0.f, 0.f};
            accS[i][j] = (f32x4){0.f, 0.f, 0.f, 0.f};
        }

    #pragma unroll
    for (int kt = 0; kt < 4; kt++) {
        int ko = kt * 32 + quad * 8;
        short8 a0 = *(short8*)&af0[kt];
        short8 a1 = *(short8*)&af1[kt];
        #pragma unroll
        for (int nt = 0; nt < 8; nt++) {
            short8 bn = *(const short8*)&Bn[(nt * 16 + ml) * LDSPAD + ko];
            accY[0][nt] = __builtin_amdgcn_mfma_f32_16x16x32_bf16(a0, bn, accY[0][nt], 0, 0, 0);
            accY[1][nt] = __builtin_amdgcn_mfma_f32_16x16x32_bf16(a1, bn, accY[1][nt], 0, 0, 0);
            short8 bs = *(const short8*)&Bs[(nt * 16 + ml) * LDSPAD + ko];
            accS[0][nt] = __builtin_amdgcn_mfma_f32_16x16x32_bf16(a0, bs, accS[0][nt], 0, 0, 0);
            accS[1][nt] = __builtin_amdgcn_mfma_f32_16x16x32_bf16(a1, bs, accS[1][nt], 0, 0, 0);
        }
    }

    float bsum[8];
    #pragma unroll
    for (int nt = 0; nt < 8; nt++) {
        int col = nt * 16 + ml;
        bsum[nt] = bias_s[col] + bias_n[col];
    }

    // ---- epilogue: B buffers dead; LDS round-trip -> coalesced slice-major stores
    __syncthreads();
    #pragma unroll
    for (int mt = 0; mt < 2; mt++) {
        int lrow0 = m0 + mt * 16 + quad * 4;
        #pragma unroll
        for (int r = 0; r < 4; r++)
            #pragma unroll
            for (int nt = 0; nt < 8; nt++) {
                Bn[(lrow0 + r) * LDSPAD + nt * 16 + ml] = f2bf(accY[mt][nt][r]);
                Bs[(lrow0 + r) * LDSPAD + nt * 16 + ml] = f2bf(accS[mt][nt][r] + bsum[nt]);
            }
    }
    __syncthreads();
    #pragma unroll
    for (int it = 0; it < 8; it++) {
        int idx = t + it * 256;
        int r = idx >> 4, seg = idx & 15;
        int gr = rowBase + r;
        if (gr < N) {
            size_t o = (size_t)(seg >> 1) * N2 + (size_t)gr * 2 + (seg & 1);
            Ys[o] = *(const uint4*)&Bn[r * LDSPAD + seg * 8];
            Ss[o] = *(const uint4*)&Bs[r * LDSPAD + seg * 8];
        }
    }
}

// ---------------------------------------------------------------- fused aggregate+combine, COLUMN-SLICED:
// block (dgrp, slice=blockIdx%8): 4 dst nodes x 16 cols. slice rides the
// round-robin block->XCD map so each XCD's Y footprint = N*32B = 3.2MB (L2-fits).
// Wave: 8 edge slots (q=lane>>3) x 8 uint32 lanes (cl=lane&7).
__global__ void k_aggc(const uint32_t* __restrict__ ys, const uint32_t* __restrict__ ss,
                       const int* __restrict__ rp, const int* __restrict__ srcs,
                       const float* __restrict__ invd, uint32_t* __restrict__ xos, int N) {
    int t = threadIdx.x;
    int lane = t & 63;
    int q = lane >> 3;         // edge slot 0..7
    int cl = lane & 7;         // uint32 (2 cols) within slice
    int slice = blockIdx.x & 7;
    int d = (blockIdx.x >> 3) * 4 + (t >> 6);
    if (d >= N) return;
    const uint32_t* yb = ys + (size_t)slice * N * 8;   // slice block
    int s = rp[d], e = rp[d + 1];
    float a0 = 0.f, a1 = 0.f;
    for (int base = s; base < e; base += 64) {
        int m = min(64, e - base);
        int idx = (lane < m) ? srcs[base + lane] : 0;
        int j = 0;
        for (; j + 32 <= m; j += 32) {     // 32 edges: 4 loads in flight/lane
            int i0 = __shfl(idx, j + q, 64);
            int i1 = __shfl(idx, j + 8 + q, 64);
            int i2 = __shfl(idx, j + 16 + q, 64);
            int i3 = __shfl(idx, j + 24 + q, 64);
            uint32_t u0 = yb[(size_t)i0 * 8 + cl];
            uint32_t u1 = yb[(size_t)i1 * 8 + cl];
            uint32_t u2 = yb[(size_t)i2 * 8 + cl];
            uint32_t u3 = yb[(size_t)i3 * 8 + cl];
            a0 += bflo(u0); a1 += bfhi(u0);
            a0 += bflo(u1); a1 += bfhi(u1);
            a0 += bflo(u2); a1 += bfhi(u2);
            a0 += bflo(u3); a1 += bfhi(u3);
        }
        for (; j + 8 <= m; j += 8) {
            int id = __shfl(idx, j + q, 64);
            uint32_t u = yb[(size_t)id * 8 + cl];
            a0 += bflo(u); a1 += bfhi(u);
        }
        if (j < m) {                       // 1..7 leftover edges
            int id = __shfl(idx, min(j + q, m - 1), 64);
            if (q < m - j) {
                uint32_t u = yb[(size_t)id * 8 + cl];
                a0 += bflo(u); a1 += bfhi(u);
            }
        }
    }
    // reduce across 8 q-slots
    a0 += __shfl_down(a0, 32, 64); a1 += __shfl_down(a1, 32, 64);
    a0 += __shfl_down(a0, 16, 64); a1 += __shfl_down(a1, 16, 64);
    a0 += __shfl_down(a0, 8, 64);  a1 += __shfl_down(a1, 8, 64);
    if (q == 0) {
        float iv = invd[d];
        size_t o = (size_t)slice * N * 8 + (size_t)d * 8 + cl;
        uint32_t su = ss[o];
        xos[o] = pack2(fmaxf(bflo(su) + a0 * iv, 0.f),
                       fmaxf(bfhi(su) + a1 * iv, 0.f));
    }
}

// ---------------------------------------------------------------- fused mean-pool + heads (256 thr/graph), slice-major read
__global__ void k_poolhead(const uint4* __restrict__ xs, const int* __restrict__ gstart,
                           const int* __restrict__ counts,
                           const float* __restrict__ Wr, const float* __restrict__ br,
                           const float* __restrict__ Wc, const float* __restrict__ bc,
                           float* __restrict__ out, int N, int G) {
    __shared__ float red[3][128];
    __shared__ float rowf[128];
    int gr = blockIdx.x, t = threadIdx.x;
    int wv = t >> 6, lane = t & 63;
    int q = lane >> 4;         // row slot 0..3
    int cl = lane & 15;        // uint4 chunk: slice = cl>>1, h = cl&1
    int s = gstart[gr], e = gstart[gr + 1];
    const size_t N2 = (size_t)N * 2;
    size_t sb = (size_t)(cl >> 1) * N2 + (cl & 1);
    float a[8] = {0.f, 0.f, 0.f, 0.f, 0.f, 0.f, 0.f, 0.f};
    for (int r0 = s + wv * 4 + q; r0 < e; r0 += 32) {
        uint4 u0 = xs[sb + (size_t)r0 * 2];
        uint4 u1 = make_uint4(0u, 0u, 0u, 0u);
        int r1 = r0 + 16;
        if (r1 < e) u1 = xs[sb + (size_t)r1 * 2];
        a[0] += bflo(u0.x) + bflo(u1.x); a[1] += bfhi(u0.x) + bfhi(u1.x);
        a[2] += bflo(u0.y) + bflo(u1.y); a[3] += bfhi(u0.y) + bfhi(u1.y);
        a[4] += bflo(u0.z) + bflo(u1.z); a[5] += bfhi(u0.z) + bfhi(u1.z);
        a[6] += bflo(u0.w) + bflo(u1.w); a[7] += bfhi(u0.w) + bfhi(u1.w);
    }
    #pragma unroll
    for (int i = 0; i < 8; i++) {
        a[i] += __shfl_down(a[i], 32, 64);
        a[i] += __shfl_down(a[i], 16, 64);
    }
    if (q == 0 && wv > 0) {
        #pragma unroll
        for (int i = 0; i < 8; i++) red[wv - 1][cl * 8 + i] = a[i];
    }
    __syncthreads();
    if (wv == 0 && q == 0) {
        float inv = 1.0f / fmaxf((float)counts[gr], 1.0f);
        #pragma unroll
        for (int i = 0; i < 8; i++) {
            float v = a[i] + red[0][cl * 8 + i] + red[1][cl * 8 + i] + red[2][cl * 8 + i];
            rowf[cl * 8 + i] = v * inv;   // col = cl*8+i (slice-major chunk == col seg)
        }
    }
    __syncthreads();
    if (t == 0) {
        float s2 = 0.f;
        for (int k = 0; k < 128; k++) s2 += rowf[k] * Wr[k];
        out[gr] = s2 + br[0];
    } else if (t <= 10) {
        int j = t - 1;
        float s2 = 0.f;
        for (int k = 0; k < 128; k++) s2 += rowf[k] * Wc[k * 10 + j];
        out[G + gr * 10 + j] = s2 + bc[j];
    }
}

// ================================================================ host
extern "C" void kernel_launch(void* const* d_in, const int* in_sizes, int n_in,
                              void* d_out, int out_size, void* d_ws, size_t ws_size,
                              hipStream_t stream) {
    const int*   nt    = (const int*)d_in[0];
    const int*   ih    = (const int*)d_in[1];
    const float* flags = (const float*)d_in[2];
    const int*   depth = (const int*)d_in[3];
    const int*   eidx  = (const int*)d_in[4];
    const int*   batch = (const int*)d_in[5];
    const float* embN  = (const float*)d_in[6];
    const float* embI  = (const float*)d_in[7];
    const float* Ws0   = (const float*)d_in[8];
    const float* bs0   = (const float*)d_in[9];
    const float* Wn0   = (const float*)d_in[10];
    const float* bn0   = (const float*)d_in[11];
    const float* Ws1   = (const float*)d_in[12];
    const float* bs1   = (const float*)d_in[13];
    const float* Wn1   = (const float*)d_in[14];
    const float* bn1   = (const float*)d_in[15];
    const float* Wr    = (const float*)d_in[16];
    const float* br    = (const float*)d_in[17];
    const float* Wc    = (const float*)d_in[18];
    const float* bc    = (const float*)d_in[19];
    float* out = (float*)d_out;

    const int N  = in_sizes[0];
    const int E  = in_sizes[4] / 2;
    const int K0 = in_sizes[8] / HIDDIM;   // 102
    const int G  = out_size / 11;          // 512
    const int* esrc = eidx;
    const int* edst = eidx + E;
    const int NBKT = (N + 255) >> 8;       // 391

    // ---- workspace carve-up
    char* w = (char*)d_ws;
    const size_t NH = (size_t)N * HIDDIM * sizeof(unsigned short);
    unsigned short* bufA = (unsigned short*)(w);            // x0, later x2 (slice-major)
    unsigned short* bufY = (unsigned short*)(w + NH);       // y (slice-major)
    unsigned short* bufS = (unsigned short*)(w + 2 * NH);   // s (slice-major)
    unsigned short* bufX1= (unsigned short*)(w + 3 * NH);   // x1 (slice-major)
    char* p = w + 4 * NH;
    unsigned short* Wt = (unsigned short*)p; p += (size_t)4 * HIDDIM * HIDDIM * 2;  // 128KB
    int2* ebuf  = (int2*)p;          p += (size_t)E * 8;
    int* srcs   = (int*)p;           p += (size_t)E * 4;
    int* rowptr = (int*)p;           p += (size_t)(N + 1) * 4;
    float* invd = (float*)p;         p += (size_t)N * 4;
    int* gstart = (int*)p;           p += (size_t)(G + 1) * 4;
    int* boff   = (int*)p;           p += (size_t)(NBKT_MAX + 1) * 4;
    int* bcur   = (int*)p;           p += (size_t)NBKT_MAX * 4;
    int* bcount = (int*)p;           p += (size_t)NBKT_MAX * 4;
    int* counts = (int*)p;           p += (size_t)G * 4;
    int* maxd   = (int*)p;           p += 4;
    const size_t zero_bytes = (size_t)(NBKT_MAX + G + 1) * 4;
    (void)n_in; (void)ws_size;

    const int nbC = (E + 4095) / 4096;               // 391
    const int nbN = (N + 255) / 256;                 // 391
    const int nbF = ((size_t)N * 16 + 255) / 256;    // 6250 (16 thr/node)
    const int nbG2 = (N + 127) / 128;
    const int nbA8 = ((N + 3) / 4) * 8;              // (dst group) x 8 col slices
    const int nbD = (N + 511) / 512;

    hipMemsetAsync(bcount, 0, zero_bytes, stream);

    // fused prep: feat | bcount | nodestats | wt
    k_prep<<<nbF + nbC + nbN + 256, 256, 0, stream>>>(
        nt, ih, flags, depth, embN, embI, edst, batch,
        Wn0, Ws0, Wn1, Ws1, K0, N, E, G,
        (uint4*)bufA, Wt, bcount, counts, maxd, nbF, nbC, nbN);

    // fused scans + depth column
    k_scan2x<<<2 + nbD, 512, 0, stream>>>(bcount, boff, bcur, rowptr,
                                          counts, gstart, depth, maxd, bufA,
                                          NBKT, N, E, G);

    k_bscatter<<<nbC, 256, 0, stream>>>(esrc, edst, bcur, ebuf, E, NBKT);
    k_build<<<NBKT, 256, 0, stream>>>(ebuf, boff, rowptr, invd, srcs, N);

    const unsigned short* Wt_n0 = Wt;
    const unsigned short* Wt_s0 = Wt + 1 * HIDDIM * HIDDIM;
    const unsigned short* Wt_n1 = Wt + 2 * HIDDIM * HIDDIM;
    const unsigned short* Wt_s1 = Wt + 3 * HIDDIM * HIDDIM;

    // layer 0: {y, s} = dual-gemm(x0) ; x1 = relu(s + invd * A y)
    k_gemm2<<<nbG2, 256, 0, stream>>>((const uint4*)bufA, Wt_n0, Wt_s0, N, bs0, bn0,
                                      (uint4*)bufY, (uint4*)bufS);
    k_aggc<<<nbA8, 256, 0, stream>>>((const uint32_t*)bufY, (const uint32_t*)bufS,
                                     rowptr, srcs, invd, (uint32_t*)bufX1, N);

    // layer 1: {y, s} = dual-gemm(x1) ; x2 = relu(s + invd * A y)  (into bufA)
    k_gemm2<<<nbG2, 256, 0, stream>>>((const uint4*)bufX1, Wt_n1, Wt_s1, N, bs1, bn1,
                                      (uint4*)bufY, (uint4*)bufS);
    k_aggc<<<nbA8, 256, 0, stream>>>((const uint32_t*)bufY, (const uint32_t*)bufS,
                                     rowptr, srcs, invd, (uint32_t*)bufA, N);

    // fused pool + heads
    k_poolhead<<<G, 256, 0, stream>>>((const uint4*)bufA, gstart, counts,
                                      Wr, br, Wc, bc, out, N, G);
}

// Round 12
// 425.196 us; speedup vs baseline: 1.5703x; 1.5703x over previous
//
#include <hip/hip_runtime.h>
#include <cstdint>
#include <cstddef>

#define HIDDIM 128
#define NGRAPH_MAX 512
#define LDSPAD 136   // 128 + 8 bf16 pad: row stride 272B (16B-aligned, bank-conflict-free frag reads)
#define NBKT_MAX 512 // coarse buckets of 256 nodes (dst>>8); N<=131072

// Feature matrices (x0/x1/x2/y/s) are stored SLICE-MAJOR:
//   slice = col/16 (8 slices), layout[slice][node][16 cols bf16]
// k_aggc block (dgrp, slice=blockIdx%8) rides round-robin block->XCD dispatch so
// each XCD's gather footprint is N*32B = 3.2MB (L2-resident). r11 verified:
// FETCH 193 -> 62 MB. r11's failure was execution (VALUBusy 60%, 8x-replicated
// per-dst overhead + shfl chains) -> r12 rewrites aggc as lane-group-per-dst.

using short8 = __attribute__((ext_vector_type(8))) short;
using f32x4  = __attribute__((ext_vector_type(4))) float;

__device__ __forceinline__ unsigned short f2bf(float x) {
    union { float f; uint32_t u; } v; v.f = x;
    uint32_t r = v.u + 0x7fffu + ((v.u >> 16) & 1u);   // RNE
    return (unsigned short)(r >> 16);
}
__device__ __forceinline__ uint32_t pack2(float a, float b) {
    return (uint32_t)f2bf(a) | ((uint32_t)f2bf(b) << 16);
}
__device__ __forceinline__ float bflo(uint32_t u) { return __uint_as_float(u << 16); }
__device__ __forceinline__ float bfhi(uint32_t u) { return __uint_as_float(u & 0xffff0000u); }

// ---------------------------------------------------------------- fused prep: feat | bcount | nodestats | wt
__global__ void k_prep(const int* __restrict__ nt, const int* __restrict__ ih,
                       const float* __restrict__ flags, const int* __restrict__ depth,
                       const float* __restrict__ embN, const float* __restrict__ embI,
                       const int* __restrict__ edst, const int* __restrict__ batch,
                       const float* __restrict__ Wn0, const float* __restrict__ Ws0,
                       const float* __restrict__ Wn1, const float* __restrict__ Ws1,
                       int K0, int N, int E, int G,
                       uint4* __restrict__ x0s, unsigned short* __restrict__ Wt,
                       int* __restrict__ bcount, int* __restrict__ counts,
                       int* __restrict__ maxd,
                       int nbF, int nbC, int nbN) {
    __shared__ int hist[NBKT_MAX];
    __shared__ int red[256];
    int b = blockIdx.x, t = threadIdx.x;
    if (b < nbF) {
        // ---- node features: 16 threads/node, one uint4 (8 bf16 cols) each, slice-major store
        int idx = b * 256 + t;
        int i = idx >> 4;
        int seg = idx & 15;
        if (i >= N) return;
        uint4 o = make_uint4(0u, 0u, 0u, 0u);
        if (seg < 8) {
            const float4* r = (const float4*)(embN + (size_t)nt[i] * 64 + seg * 8);
            float4 v0 = r[0], v1 = r[1];
            o.x = pack2(v0.x, v0.y); o.y = pack2(v0.z, v0.w);
            o.z = pack2(v1.x, v1.y); o.w = pack2(v1.z, v1.w);
        } else if (seg < 12) {
            const float4* r = (const float4*)(embI + (size_t)ih[i] * 32 + (seg - 8) * 8);
            float4 v0 = r[0], v1 = r[1];
            o.x = pack2(v0.x, v0.y); o.y = pack2(v0.z, v0.w);
            o.z = pack2(v1.x, v1.y); o.w = pack2(v1.z, v1.w);
        } else if (seg == 12) {
            const float* fp = flags + (size_t)i * 5;
            o.x = pack2(fp[0], fp[1]);
            o.y = pack2(fp[2], fp[3]);
            o.z = pack2(fp[4], 0.f);   // col101 (depth) written by k_scan2x
        }
        // slice-major: slice = seg>>1, h = seg&1
        x0s[(size_t)(seg >> 1) * (N * 2) + (size_t)i * 2 + (seg & 1)] = o;
    } else if (b < nbF + nbC) {
        hist[t] = 0; hist[t + 256] = 0;
        __syncthreads();
        int c0 = (b - nbF) * 4096;
        int ce = min(4096, E - c0);
        for (int i = t; i < ce; i += 256)
            atomicAdd(&hist[edst[c0 + i] >> 8], 1);
        __syncthreads();
        for (int bb = t; bb < NBKT_MAX; bb += 256)
            if (hist[bb]) atomicAdd(&bcount[bb], hist[bb]);
    } else if (b < nbF + nbC + nbN) {
        for (int g = t; g < G; g += 256) hist[g] = 0;
        __syncthreads();
        int i = (b - nbF - nbC) * 256 + t;
        int d = 0;
        if (i < N) {
            atomicAdd(&hist[batch[i]], 1);
            d = depth[i];
        }
        red[t] = d;
        __syncthreads();
        for (int off = 128; off > 0; off >>= 1) {
            if (t < off) red[t] = max(red[t], red[t + off]);
            __syncthreads();
        }
        if (t == 0) atomicMax(maxd, red[0]);
        for (int g = t; g < G; g += 256)
            if (hist[g]) atomicAdd(&counts[g], hist[g]);
    } else {
        int idx = (b - nbF - nbC - nbN) * 256 + t;   // 65536 total
        int mat = idx >> 14;
        int rem = idx & 16383;
        int n = rem >> 7, k = rem & 127;
        const float* W = (mat == 0) ? Wn0 : (mat == 1) ? Ws0 : (mat == 2) ? Wn1 : Ws1;
        int K = (mat < 2) ? K0 : HIDDIM;
        Wt[(size_t)mat * HIDDIM * HIDDIM + n * HIDDIM + k] =
            (k < K) ? f2bf(W[(size_t)k * HIDDIM + n]) : (unsigned short)0;
    }
}

// ---------------------------------------------------------------- fused scans + depth column (512 thr)
__global__ void k_scan2x(const int* __restrict__ bcount, int* __restrict__ boff,
                         int* __restrict__ bcur, int* __restrict__ rowptr,
                         const int* __restrict__ counts, int* __restrict__ gstart,
                         const int* __restrict__ depth, const int* __restrict__ maxd,
                         unsigned short* __restrict__ x0s,
                         int nbkt, int N, int E, int G) {
    __shared__ int sd[512];
    int b = blockIdx.x, t = threadIdx.x;
    if (b == 0) {
        int v = (t < nbkt) ? bcount[t] : 0;
        sd[t] = v;
        __syncthreads();
        for (int off = 1; off < 512; off <<= 1) {
            int x = (t >= off) ? sd[t - off] : 0;
            __syncthreads();
            sd[t] += x;
            __syncthreads();
        }
        if (t < nbkt) { boff[t] = sd[t] - v; bcur[t] = sd[t] - v; }
        if (t == 0) { boff[nbkt] = E; rowptr[N] = E; }
    } else if (b == 1) {
        int v = (t < G) ? counts[t] : 0;
        sd[t] = v;
        __syncthreads();
        for (int off = 1; off < 512; off <<= 1) {
            int x = (t >= off) ? sd[t - off] : 0;
            __syncthreads();
            sd[t] += x;
            __syncthreads();
        }
        if (t < G) gstart[t] = sd[t] - v;
        if (t == G - 1) gstart[G] = sd[t];
    } else {
        int i = (b - 2) * 512 + t;
        if (i < N) {
            float md = fmaxf((float)(*maxd), 1.0f);
            // col 101 -> slice 6, within-slice col 5
            x0s[(size_t)6 * N * 16 + (size_t)i * 16 + 5] = f2bf((float)depth[i] / md);
        }
    }
}

// ---------------------------------------------------------------- bucket scatter (unchanged)
__global__ void k_bscatter(const int* __restrict__ src, const int* __restrict__ dst,
                           int* __restrict__ bcur, int2* __restrict__ ebuf, int E, int nbkt) {
    __shared__ int2 stage[4096];        // 32 KB
    __shared__ int hist[NBKT_MAX];
    __shared__ int ofs[NBKT_MAX];
    __shared__ int cur[NBKT_MAX];
    __shared__ int gbase[NBKT_MAX];
    __shared__ int scanbuf[256];
    int t = threadIdx.x;
    int c0 = blockIdx.x * 4096;
    int ce = min(4096, E - c0);

    hist[t] = 0; hist[t + 256] = 0;
    __syncthreads();
    for (int i = t; i < ce; i += 256)
        atomicAdd(&hist[dst[c0 + i] >> 8], 1);
    __syncthreads();
    int h2a = hist[2 * t], h2b = hist[2 * t + 1];
    int ps = h2a + h2b;
    scanbuf[t] = ps;
    __syncthreads();
    for (int off = 1; off < 256; off <<= 1) {
        int x = (t >= off) ? scanbuf[t - off] : 0;
        __syncthreads();
        scanbuf[t] += x;
        __syncthreads();
    }
    int ex = scanbuf[t] - ps;
    ofs[2 * t] = ex;           cur[2 * t] = ex;
    ofs[2 * t + 1] = ex + h2a; cur[2 * t + 1] = ex + h2a;
    __syncthreads();
    for (int i = t; i < ce; i += 256) {
        int d = dst[c0 + i];
        int p = atomicAdd(&cur[d >> 8], 1);
        stage[p] = make_int2(src[c0 + i], d);
    }
    __syncthreads();
    for (int b = t; b < nbkt; b += 256) {
        int c = hist[b];
        gbase[b] = c ? atomicAdd(&bcur[b], c) : 0;
    }
    __syncthreads();
    for (int j = t; j < ce; j += 256) {
        int2 p = stage[j];
        int b = p.y >> 8;
        ebuf[gbase[b] + (j - ofs[b])] = p;
    }
}

// ---------------------------------------------------------------- per-bucket CSR build (unchanged)
__global__ void k_build(const int2* __restrict__ ebuf, const int* __restrict__ boff,
                        int* __restrict__ rowptr, float* __restrict__ invd,
                        int* __restrict__ srcs, int N) {
    __shared__ int ldeg[256];
    __shared__ int lofs[256];
    __shared__ int lcur[256];
    int b = blockIdx.x, t = threadIdx.x;
    int n0 = b << 8;
    int s = boff[b], e = boff[b + 1];
    ldeg[t] = 0;
    __syncthreads();
    for (int i = s + t; i < e; i += 256)
        atomicAdd(&ldeg[ebuf[i].y & 255], 1);
    __syncthreads();
    int v = ldeg[t];
    lofs[t] = v;
    __syncthreads();
    for (int off = 1; off < 256; off <<= 1) {
        int x = (t >= off) ? lofs[t - off] : 0;
        __syncthreads();
        lofs[t] += x;
        __syncthreads();
    }
    int excl = lofs[t] - v;
    int node = n0 + t;
    if (node < N) {
        rowptr[node] = s + excl;
        invd[node] = 1.0f / (float)max(v, 1);
    }
    lcur[t] = excl;
    __syncthreads();
    for (int i = s + t; i < e; i += 256) {
        int2 p = ebuf[i];
        int slot = atomicAdd(&lcur[p.y & 255], 1);
        srcs[s + slot] = p.x;
    }
}

// ---------------------------------------------------------------- dual bf16 MFMA GEMM (K=128 fixed), slice-major I/O
__global__ __launch_bounds__(256, 2) void k_gemm2(
    const uint4* __restrict__ Xs,
    const unsigned short* __restrict__ Wtn, const unsigned short* __restrict__ Wts,
    int N, const float* __restrict__ bias_s, const float* __restrict__ bias_n,
    uint4* __restrict__ Ys, uint4* __restrict__ Ss) {
    __shared__ unsigned short Bn[128 * LDSPAD];   // 34.8 KB
    __shared__ unsigned short Bs[128 * LDSPAD];   // 34.8 KB
    int t = threadIdx.x;
    int rowBase = blockIdx.x << 7;
    const size_t N2 = (size_t)N * 2;

    #pragma unroll
    for (int it = 0; it < 8; it++) {
        int idx = t + it * 256;
        int n = idx >> 4, seg = idx & 15;
        *(uint4*)&Bn[n * LDSPAD + seg * 8] = *(const uint4*)(Wtn + n * HIDDIM + seg * 8);
        *(uint4*)&Bs[n * LDSPAD + seg * 8] = *(const uint4*)(Wts + n * HIDDIM + seg * 8);
    }

    int lane = t & 63;
    int wv = t >> 6;
    int ml = lane & 15;
    int quad = lane >> 4;
    int m0 = wv * 32;

    // hoisted A-frags; col group kt*32+quad*8 -> slice 2kt+(quad>>1), h=quad&1
    int gr0 = rowBase + m0 + ml;
    int gr1 = gr0 + 16;
    uint4 af0[4], af1[4];
    #pragma unroll
    for (int kt = 0; kt < 4; kt++) {
        uint4 z = make_uint4(0u, 0u, 0u, 0u);
        size_t sb = (size_t)(2 * kt + (quad >> 1)) * N2 + (quad & 1);
        af0[kt] = (gr0 < N) ? Xs[sb + (size_t)gr0 * 2] : z;
        af1[kt] = (gr1 < N) ? Xs[sb + (size_t)gr1 * 2] : z;
    }
    __syncthreads();

    f32x4 accY[2][8], accS[2][8];
    #pragma unroll
    for (int i = 0; i < 2; i++)
        #pragma unroll
        for (int j = 0; j < 8; j++) {
            accY[i][j] = (f32x4){0.f, 0.f, 0.f, 0.f};
            accS[i][j] = (f32x4){0.f, 0.f, 0.f, 0.f};
        }

    #pragma unroll
    for (int kt = 0; kt < 4; kt++) {
        int ko = kt * 32 + quad * 8;
        short8 a0 = *(short8*)&af0[kt];
        short8 a1 = *(short8*)&af1[kt];
        #pragma unroll
        for (int nt = 0; nt < 8; nt++) {
            short8 bn = *(const short8*)&Bn[(nt * 16 + ml) * LDSPAD + ko];
            accY[0][nt] = __builtin_amdgcn_mfma_f32_16x16x32_bf16(a0, bn, accY[0][nt], 0, 0, 0);
            accY[1][nt] = __builtin_amdgcn_mfma_f32_16x16x32_bf16(a1, bn, accY[1][nt], 0, 0, 0);
            short8 bs = *(const short8*)&Bs[(nt * 16 + ml) * LDSPAD + ko];
            accS[0][nt] = __builtin_amdgcn_mfma_f32_16x16x32_bf16(a0, bs, accS[0][nt], 0, 0, 0);
            accS[1][nt] = __builtin_amdgcn_mfma_f32_16x16x32_bf16(a1, bs, accS[1][nt], 0, 0, 0);
        }
    }

    float bsum[8];
    #pragma unroll
    for (int nt = 0; nt < 8; nt++) {
        int col = nt * 16 + ml;
        bsum[nt] = bias_s[col] + bias_n[col];
    }

    // ---- epilogue: B buffers dead; LDS round-trip -> coalesced slice-major stores
    __syncthreads();
    #pragma unroll
    for (int mt = 0; mt < 2; mt++) {
        int lrow0 = m0 + mt * 16 + quad * 4;
        #pragma unroll
        for (int r = 0; r < 4; r++)
            #pragma unroll
            for (int nt = 0; nt < 8; nt++) {
                Bn[(lrow0 + r) * LDSPAD + nt * 16 + ml] = f2bf(accY[mt][nt][r]);
                Bs[(lrow0 + r) * LDSPAD + nt * 16 + ml] = f2bf(accS[mt][nt][r] + bsum[nt]);
            }
    }
    __syncthreads();
    #pragma unroll
    for (int it = 0; it < 8; it++) {
        int idx = t + it * 256;
        int r = idx >> 4, seg = idx & 15;
        int gr = rowBase + r;
        if (gr < N) {
            size_t o = (size_t)(seg >> 1) * N2 + (size_t)gr * 2 + (seg & 1);
            Ys[o] = *(const uint4*)&Bn[r * LDSPAD + seg * 8];
            Ss[o] = *(const uint4*)&Bs[r * LDSPAD + seg * 8];
        }
    }
}

// ---------------------------------------------------------------- fused aggregate+combine, COLUMN-SLICED v2:
// block = (dgrp, slice=blockIdx%8): 32 dst x 16 cols. An 8-lane GROUP owns one
// dst (cl = lane&7 -> 2 cols); edges walked sequentially, 4-deep unrolled.
// No shfl, no cross-lane reduce (r11 lesson: 8x-replicated per-dst fixed
// overhead + shfl chains made slicing issue-bound at VALUBusy 60%).
// invd/ss/xo accesses are 256B/wave fully coalesced (consecutive ds = consecutive d).
__global__ void k_aggc(const uint32_t* __restrict__ ys, const uint32_t* __restrict__ ss,
                       const int* __restrict__ rp, const int* __restrict__ srcs,
                       const float* __restrict__ invd, uint32_t* __restrict__ xos, int N) {
    int t = threadIdx.x;
    int lane = t & 63;
    int ds = lane >> 3;        // dst slot 0..7 within wave
    int cl = lane & 7;         // uint32 (2 cols) within slice
    int slice = blockIdx.x & 7;
    int d = (blockIdx.x >> 3) * 32 + (t >> 6) * 8 + ds;
    if (d >= N) return;
    const uint32_t* yb = ys + (size_t)slice * ((size_t)N * 8) + cl;
    int s = rp[d], e = rp[d + 1];
    float a0 = 0.f, a1 = 0.f;
    int j = s;
    for (; j + 4 <= e; j += 4) {
        int i0 = srcs[j], i1 = srcs[j + 1], i2 = srcs[j + 2], i3 = srcs[j + 3];
        uint32_t u0 = yb[(uint32_t)i0 * 8u];
        uint32_t u1 = yb[(uint32_t)i1 * 8u];
        uint32_t u2 = yb[(uint32_t)i2 * 8u];
        uint32_t u3 = yb[(uint32_t)i3 * 8u];
        a0 += bflo(u0); a1 += bfhi(u0);
        a0 += bflo(u1); a1 += bfhi(u1);
        a0 += bflo(u2); a1 += bfhi(u2);
        a0 += bflo(u3); a1 += bfhi(u3);
    }
    for (; j < e; j++) {
        uint32_t u = yb[(uint32_t)srcs[j] * 8u];
        a0 += bflo(u); a1 += bfhi(u);
    }
    float iv = invd[d];
    size_t o = (size_t)slice * ((size_t)N * 8) + (size_t)d * 8 + cl;
    uint32_t su = ss[o];
    xos[o] = pack2(fmaxf(bflo(su) + a0 * iv, 0.f),
                   fmaxf(bfhi(su) + a1 * iv, 0.f));
}

// ---------------------------------------------------------------- fused mean-pool + heads (256 thr/graph), slice-major read
__global__ void k_poolhead(const uint4* __restrict__ xs, const int* __restrict__ gstart,
                           const int* __restrict__ counts,
                           const float* __restrict__ Wr, const float* __restrict__ br,
                           const float* __restrict__ Wc, const float* __restrict__ bc,
                           float* __restrict__ out, int N, int G) {
    __shared__ float red[3][128];
    __shared__ float rowf[128];
    int gr = blockIdx.x, t = threadIdx.x;
    int wv = t >> 6, lane = t & 63;
    int q = lane >> 4;         // row slot 0..3
    int cl = lane & 15;        // uint4 chunk: slice = cl>>1, h = cl&1
    int s = gstart[gr], e = gstart[gr + 1];
    const size_t N2 = (size_t)N * 2;
    size_t sb = (size_t)(cl >> 1) * N2 + (cl & 1);
    float a[8] = {0.f, 0.f, 0.f, 0.f, 0.f, 0.f, 0.f, 0.f};
    for (int r0 = s + wv * 4 + q; r0 < e; r0 += 32) {
        uint4 u0 = xs[sb + (size_t)r0 * 2];
        uint4 u1 = make_uint4(0u, 0u, 0u, 0u);
        int r1 = r0 + 16;
        if (r1 < e) u1 = xs[sb + (size_t)r1 * 2];
        a[0] += bflo(u0.x) + bflo(u1.x); a[1] += bfhi(u0.x) + bfhi(u1.x);
        a[2] += bflo(u0.y) + bflo(u1.y); a[3] += bfhi(u0.y) + bfhi(u1.y);
        a[4] += bflo(u0.z) + bflo(u1.z); a[5] += bfhi(u0.z) + bfhi(u1.z);
        a[6] += bflo(u0.w) + bflo(u1.w); a[7] += bfhi(u0.w) + bfhi(u1.w);
    }
    #pragma unroll
    for (int i = 0; i < 8; i++) {
        a[i] += __shfl_down(a[i], 32, 64);
        a[i] += __shfl_down(a[i], 16, 64);
    }
    if (q == 0 && wv > 0) {
        #pragma unroll
        for (int i = 0; i < 8; i++) red[wv - 1][cl * 8 + i] = a[i];
    }
    __syncthreads();
    if (wv == 0 && q == 0) {
        float inv = 1.0f / fmaxf((float)counts[gr], 1.0f);
        #pragma unroll
        for (int i = 0; i < 8; i++) {
            float v = a[i] + red[0][cl * 8 + i] + red[1][cl * 8 + i] + red[2][cl * 8 + i];
            rowf[cl * 8 + i] = v * inv;   // col = cl*8+i (slice-major chunk == col seg)
        }
    }
    __syncthreads();
    if (t == 0) {
        float s2 = 0.f;
        for (int k = 0; k < 128; k++) s2 += rowf[k] * Wr[k];
        out[gr] = s2 + br[0];
    } else if (t <= 10) {
        int j = t - 1;
        float s2 = 0.f;
        for (int k = 0; k < 128; k++) s2 += rowf[k] * Wc[k * 10 + j];
        out[G + gr * 10 + j] = s2 + bc[j];
    }
}

// ================================================================ host
extern "C" void kernel_launch(void* const* d_in, const int* in_sizes, int n_in,
                              void* d_out, int out_size, void* d_ws, size_t ws_size,
                              hipStream_t stream) {
    const int*   nt    = (const int*)d_in[0];
    const int*   ih    = (const int*)d_in[1];
    const float* flags = (const float*)d_in[2];
    const int*   depth = (const int*)d_in[3];
    const int*   eidx  = (const int*)d_in[4];
    const int*   batch = (const int*)d_in[5];
    const float* embN  = (const float*)d_in[6];
    const float* embI  = (const float*)d_in[7];
    const float* Ws0   = (const float*)d_in[8];
    const float* bs0   = (const float*)d_in[9];
    const float* Wn0   = (const float*)d_in[10];
    const float* bn0   = (const float*)d_in[11];
    const float* Ws1   = (const float*)d_in[12];
    const float* bs1   = (const float*)d_in[13];
    const float* Wn1   = (const float*)d_in[14];
    const float* bn1   = (const float*)d_in[15];
    const float* Wr    = (const float*)d_in[16];
    const float* br    = (const float*)d_in[17];
    const float* Wc    = (const float*)d_in[18];
    const float* bc    = (const float*)d_in[19];
    float* out = (float*)d_out;

    const int N  = in_sizes[0];
    const int E  = in_sizes[4] / 2;
    const int K0 = in_sizes[8] / HIDDIM;   // 102
    const int G  = out_size / 11;          // 512
    const int* esrc = eidx;
    const int* edst = eidx + E;
    const int NBKT = (N + 255) >> 8;       // 391

    // ---- workspace carve-up
    char* w = (char*)d_ws;
    const size_t NH = (size_t)N * HIDDIM * sizeof(unsigned short);
    unsigned short* bufA = (unsigned short*)(w);            // x0, later x2 (slice-major)
    unsigned short* bufY = (unsigned short*)(w + NH);       // y (slice-major)
    unsigned short* bufS = (unsigned short*)(w + 2 * NH);   // s (slice-major)
    unsigned short* bufX1= (unsigned short*)(w + 3 * NH);   // x1 (slice-major)
    char* p = w + 4 * NH;
    unsigned short* Wt = (unsigned short*)p; p += (size_t)4 * HIDDIM * HIDDIM * 2;  // 128KB
    int2* ebuf  = (int2*)p;          p += (size_t)E * 8;
    int* srcs   = (int*)p;           p += (size_t)E * 4;
    int* rowptr = (int*)p;           p += (size_t)(N + 1) * 4;
    float* invd = (float*)p;         p += (size_t)N * 4;
    int* gstart = (int*)p;           p += (size_t)(G + 1) * 4;
    int* boff   = (int*)p;           p += (size_t)(NBKT_MAX + 1) * 4;
    int* bcur   = (int*)p;           p += (size_t)NBKT_MAX * 4;
    int* bcount = (int*)p;           p += (size_t)NBKT_MAX * 4;
    int* counts = (int*)p;           p += (size_t)G * 4;
    int* maxd   = (int*)p;           p += 4;
    const size_t zero_bytes = (size_t)(NBKT_MAX + G + 1) * 4;
    (void)n_in; (void)ws_size;

    const int nbC = (E + 4095) / 4096;               // 391
    const int nbN = (N + 255) / 256;                 // 391
    const int nbF = ((size_t)N * 16 + 255) / 256;    // 6250 (16 thr/node)
    const int nbG2 = (N + 127) / 128;
    const int nbA8 = ((N + 31) / 32) * 8;            // (32-dst group) x 8 col slices
    const int nbD = (N + 511) / 512;

    hipMemsetAsync(bcount, 0, zero_bytes, stream);

    // fused prep: feat | bcount | nodestats | wt
    k_prep<<<nbF + nbC + nbN + 256, 256, 0, stream>>>(
        nt, ih, flags, depth, embN, embI, edst, batch,
        Wn0, Ws0, Wn1, Ws1, K0, N, E, G,
        (uint4*)bufA, Wt, bcount, counts, maxd, nbF, nbC, nbN);

    // fused scans + depth column
    k_scan2x<<<2 + nbD, 512, 0, stream>>>(bcount, boff, bcur, rowptr,
                                          counts, gstart, depth, maxd, bufA,
                                          NBKT, N, E, G);

    k_bscatter<<<nbC, 256, 0, stream>>>(esrc, edst, bcur, ebuf, E, NBKT);
    k_build<<<NBKT, 256, 0, stream>>>(ebuf, boff, rowptr, invd, srcs, N);

    const unsigned short* Wt_n0 = Wt;
    const unsigned short* Wt_s0 = Wt + 1 * HIDDIM * HIDDIM;
    const unsigned short* Wt_n1 = Wt + 2 * HIDDIM * HIDDIM;
    const unsigned short* Wt_s1 = Wt + 3 * HIDDIM * HIDDIM;

    // layer 0: {y, s} = dual-gemm(x0) ; x1 = relu(s + invd * A y)
    k_gemm2<<<nbG2, 256, 0, stream>>>((const uint4*)bufA, Wt_n0, Wt_s0, N, bs0, bn0,
                                      (uint4*)bufY, (uint4*)bufS);
    k_aggc<<<nbA8, 256, 0, stream>>>((const uint32_t*)bufY, (const uint32_t*)bufS,
                                     rowptr, srcs, invd, (uint32_t*)bufX1, N);

    // layer 1: {y, s} = dual-gemm(x1) ; x2 = relu(s + invd * A y)  (into bufA)
    k_gemm2<<<nbG2, 256, 0, stream>>>((const uint4*)bufX1, Wt_n1, Wt_s1, N, bs1, bn1,
                                      (uint4*)bufY, (uint4*)bufS);
    k_aggc<<<nbA8, 256, 0, stream>>>((const uint32_t*)bufY, (const uint32_t*)bufS,
                                     rowptr, srcs, invd, (uint32_t*)bufA, N);

    // fused pool + heads
    k_poolhead<<<G, 256, 0, stream>>>((const uint4*)bufA, gstart, counts,
                                      Wr, br, Wc, bc, out, N, G);
}

// Round 13
// 342.514 us; speedup vs baseline: 1.9494x; 1.2414x over previous
//
#include <hip/hip_runtime.h>
#include <cstdint>
#include <cstddef>

#define HIDDIM 128
#define NGRAPH_MAX 512
#define LDSPAD 136   // 128 + 8 bf16 pad: row stride 272B (16B-aligned, bank-conflict-free frag reads)
#define NBKT_MAX 512 // coarse buckets of 256 nodes (dst>>8); N<=131072

// r13: reverted to row-major feature layout (r12 falsified column-slicing: sliced
// gather is latency/srcs-replication-bound at 94µs vs row-major's traffic-bound 62µs).
// New: algebraic reorder invd*(A·(xW)) == (invd*(A·x))W -> aggregate x FIRST, then
// one dual-input GEMM x_next = relu(x@Ws + ax@Wn + b). Deletes Y/S intermediates
// (-51MB/layer) and halves GEMM accumulators. ebuf packed to uint32 (src|dlow<<24).

using short8 = __attribute__((ext_vector_type(8))) short;
using f32x4  = __attribute__((ext_vector_type(4))) float;

__device__ __forceinline__ unsigned short f2bf(float x) {
    union { float f; uint32_t u; } v; v.f = x;
    uint32_t r = v.u + 0x7fffu + ((v.u >> 16) & 1u);   // RNE
    return (unsigned short)(r >> 16);
}
__device__ __forceinline__ uint32_t pack2(float a, float b) {
    return (uint32_t)f2bf(a) | ((uint32_t)f2bf(b) << 16);
}
__device__ __forceinline__ float bflo(uint32_t u) { return __uint_as_float(u << 16); }
__device__ __forceinline__ float bfhi(uint32_t u) { return __uint_as_float(u & 0xffff0000u); }

// ---------------------------------------------------------------- fused prep: feat | bcount | nodestats | wt
// block ranges: [0,nbF) feat(16 thr/node) ; [nbF,+nbC) bcount ; [+nbN) nodestats ; [+256) wt
__global__ void k_prep(const int* __restrict__ nt, const int* __restrict__ ih,
                       const float* __restrict__ flags, const int* __restrict__ depth,
                       const float* __restrict__ embN, const float* __restrict__ embI,
                       const int* __restrict__ edst, const int* __restrict__ batch,
                       const float* __restrict__ Wn0, const float* __restrict__ Ws0,
                       const float* __restrict__ Wn1, const float* __restrict__ Ws1,
                       int K0, int N, int E, int G,
                       unsigned short* __restrict__ x0, unsigned short* __restrict__ Wt,
                       int* __restrict__ bcount, int* __restrict__ counts,
                       int* __restrict__ maxd,
                       int nbF, int nbC, int nbN) {
    __shared__ int hist[NBKT_MAX];
    __shared__ int red[256];
    int b = blockIdx.x, t = threadIdx.x;
    if (b < nbF) {
        // ---- node features: 16 threads/node, one uint4 (8 bf16 cols) each
        int idx = b * 256 + t;
        int i = idx >> 4;
        int seg = idx & 15;
        if (i >= N) return;
        uint4 o = make_uint4(0u, 0u, 0u, 0u);
        if (seg < 8) {
            const float4* r = (const float4*)(embN + (size_t)nt[i] * 64 + seg * 8);
            float4 v0 = r[0], v1 = r[1];
            o.x = pack2(v0.x, v0.y); o.y = pack2(v0.z, v0.w);
            o.z = pack2(v1.x, v1.y); o.w = pack2(v1.z, v1.w);
        } else if (seg < 12) {
            const float4* r = (const float4*)(embI + (size_t)ih[i] * 32 + (seg - 8) * 8);
            float4 v0 = r[0], v1 = r[1];
            o.x = pack2(v0.x, v0.y); o.y = pack2(v0.z, v0.w);
            o.z = pack2(v1.x, v1.y); o.w = pack2(v1.z, v1.w);
        } else if (seg == 12) {
            // cols 96..103: 5 flags, col101=0 (depth written by k_scan2x), 102..103=0
            const float* fp = flags + (size_t)i * 5;
            o.x = pack2(fp[0], fp[1]);
            o.y = pack2(fp[2], fp[3]);
            o.z = pack2(fp[4], 0.f);
        } // seg 13..15: zeros
        *(uint4*)(x0 + (size_t)i * HIDDIM + seg * 8) = o;
    } else if (b < nbF + nbC) {
        // ---- edge bucket histogram
        hist[t] = 0; hist[t + 256] = 0;
        __syncthreads();
        int c0 = (b - nbF) * 4096;
        int ce = min(4096, E - c0);
        for (int i = t; i < ce; i += 256)
            atomicAdd(&hist[edst[c0 + i] >> 8], 1);
        __syncthreads();
        for (int bb = t; bb < NBKT_MAX; bb += 256)
            if (hist[bb]) atomicAdd(&bcount[bb], hist[bb]);
    } else if (b < nbF + nbC + nbN) {
        // ---- graph counts + max depth
        for (int g = t; g < G; g += 256) hist[g] = 0;
        __syncthreads();
        int i = (b - nbF - nbC) * 256 + t;
        int d = 0;
        if (i < N) {
            atomicAdd(&hist[batch[i]], 1);
            d = depth[i];
        }
        red[t] = d;
        __syncthreads();
        for (int off = 128; off > 0; off >>= 1) {
            if (t < off) red[t] = max(red[t], red[t + off]);
            __syncthreads();
        }
        if (t == 0) atomicMax(maxd, red[0]);
        for (int g = t; g < G; g += 256)
            if (hist[g]) atomicAdd(&counts[g], hist[g]);
    } else {
        // ---- weight pre-transpose: Wt[mat][n][k] bf16, K zero-padded to 128
        int idx = (b - nbF - nbC - nbN) * 256 + t;   // 65536 total
        int mat = idx >> 14;
        int rem = idx & 16383;
        int n = rem >> 7, k = rem & 127;
        const float* W = (mat == 0) ? Wn0 : (mat == 1) ? Ws0 : (mat == 2) ? Wn1 : Ws1;
        int K = (mat < 2) ? K0 : HIDDIM;
        Wt[(size_t)mat * HIDDIM * HIDDIM + n * HIDDIM + k] =
            (k < K) ? f2bf(W[(size_t)k * HIDDIM + n]) : (unsigned short)0;
    }
}

// ---------------------------------------------------------------- fused scans + depth column (512 thr)
__global__ void k_scan2x(const int* __restrict__ bcount, int* __restrict__ boff,
                         int* __restrict__ bcur, int* __restrict__ rowptr,
                         const int* __restrict__ counts, int* __restrict__ gstart,
                         const int* __restrict__ depth, const int* __restrict__ maxd,
                         unsigned short* __restrict__ x0,
                         int nbkt, int N, int E, int G) {
    __shared__ int sd[512];
    int b = blockIdx.x, t = threadIdx.x;
    if (b == 0) {
        int v = (t < nbkt) ? bcount[t] : 0;
        sd[t] = v;
        __syncthreads();
        for (int off = 1; off < 512; off <<= 1) {
            int x = (t >= off) ? sd[t - off] : 0;
            __syncthreads();
            sd[t] += x;
            __syncthreads();
        }
        if (t < nbkt) { boff[t] = sd[t] - v; bcur[t] = sd[t] - v; }
        if (t == 0) { boff[nbkt] = E; rowptr[N] = E; }
    } else if (b == 1) {
        int v = (t < G) ? counts[t] : 0;
        sd[t] = v;
        __syncthreads();
        for (int off = 1; off < 512; off <<= 1) {
            int x = (t >= off) ? sd[t - off] : 0;
            __syncthreads();
            sd[t] += x;
            __syncthreads();
        }
        if (t < G) gstart[t] = sd[t] - v;
        if (t == G - 1) gstart[G] = sd[t];
    } else {
        int i = (b - 2) * 512 + t;
        if (i < N) {
            float md = fmaxf((float)(*maxd), 1.0f);
            x0[(size_t)i * HIDDIM + 101] = f2bf((float)depth[i] / md);
        }
    }
}

// ---------------------------------------------------------------- bucket scatter: LDS-sort 4096-edge chunk,
// per-(block,bucket) global reservation, coalesced run writes. ebuf packed uint32
// (src | (dst&255)<<24; src < 2^24) -> half the r9 ebuf traffic + LDS stage.
__global__ void k_bscatter(const int* __restrict__ src, const int* __restrict__ dst,
                           int* __restrict__ bcur, uint32_t* __restrict__ ebuf, int E, int nbkt) {
    __shared__ uint32_t stage[4096];    // 16 KB
    __shared__ int hist[NBKT_MAX];
    __shared__ int ofs[NBKT_MAX];
    __shared__ int cur[NBKT_MAX];
    __shared__ int gbase[NBKT_MAX];
    __shared__ int scanbuf[256];
    int t = threadIdx.x;
    int c0 = blockIdx.x * 4096;
    int ce = min(4096, E - c0);

    hist[t] = 0; hist[t + 256] = 0;
    __syncthreads();
    for (int i = t; i < ce; i += 256)
        atomicAdd(&hist[dst[c0 + i] >> 8], 1);
    __syncthreads();
    int h2a = hist[2 * t], h2b = hist[2 * t + 1];
    int ps = h2a + h2b;
    scanbuf[t] = ps;
    __syncthreads();
    for (int off = 1; off < 256; off <<= 1) {
        int x = (t >= off) ? scanbuf[t - off] : 0;
        __syncthreads();
        scanbuf[t] += x;
        __syncthreads();
    }
    int ex = scanbuf[t] - ps;
    ofs[2 * t] = ex;           cur[2 * t] = ex;
    ofs[2 * t + 1] = ex + h2a; cur[2 * t + 1] = ex + h2a;
    __syncthreads();
    for (int i = t; i < ce; i += 256) {
        int d = dst[c0 + i];
        int p = atomicAdd(&cur[d >> 8], 1);
        stage[p] = (uint32_t)src[c0 + i] | ((uint32_t)(d & 255) << 24);
    }
    __syncthreads();
    for (int b = t; b < nbkt; b += 256) {
        int c = hist[b];
        gbase[b] = c ? atomicAdd(&bcur[b], c) : 0;
    }
    __syncthreads();
    for (int j = t; j < ce; j += 256) {
        uint32_t p = stage[j];
        // recover bucket: need dst>>8; stage order groups by bucket, use ofs table
        // find bucket via binary search would be slow -- instead store bucket implicitly:
        // j lies in [ofs[b], ofs[b]+hist[b]); recover b by segment: precomputed per j is
        // not available, so carry bucket in upper bits is not possible (used by dlow).
        // Use: bucket of stage slot = dst>>8 where dst = (gbase lookup). Simplest: refetch
        // bucket from a parallel LDS array.
        // (handled below -- see bkt[] array)
        (void)p;
        break;
    }
    // NOTE: we need the bucket id per staged slot for the flush. Rebuild it from ofs[]:
    // each thread walks its strided slots; bucket found by comparing against ofs via
    // a per-slot bucket array filled during placement.
    __syncthreads();
    // Second placement pass fills bucket ids (reuse scanbuf region is too small; use
    // a dedicated walk: since slots within a bucket are contiguous, thread t scans
    // buckets round-robin and flushes whole runs).
    for (int b = t; b < nbkt; b += 256) {
        int cnt = hist[b];
        if (!cnt) continue;
        int lo = ofs[b];
        int gb = gbase[b];
        for (int k = 0; k < cnt; k++)
            ebuf[gb + k] = stage[lo + k];
    }
}

// ---------------------------------------------------------------- per-bucket CSR build: deg, rowptr, invd, srcs
__global__ void k_build(const uint32_t* __restrict__ ebuf, const int* __restrict__ boff,
                        int* __restrict__ rowptr, float* __restrict__ invd,
                        int* __restrict__ srcs, int N) {
    __shared__ int ldeg[256];
    __shared__ int lofs[256];
    __shared__ int lcur[256];
    int b = blockIdx.x, t = threadIdx.x;
    int n0 = b << 8;
    int s = boff[b], e = boff[b + 1];
    ldeg[t] = 0;
    __syncthreads();
    for (int i = s + t; i < e; i += 256)
        atomicAdd(&ldeg[ebuf[i] >> 24], 1);
    __syncthreads();
    int v = ldeg[t];
    lofs[t] = v;
    __syncthreads();
    for (int off = 1; off < 256; off <<= 1) {
        int x = (t >= off) ? lofs[t - off] : 0;
        __syncthreads();
        lofs[t] += x;
        __syncthreads();
    }
    int excl = lofs[t] - v;
    int node = n0 + t;
    if (node < N) {
        rowptr[node] = s + excl;
        invd[node] = 1.0f / (float)max(v, 1);
    }
    lcur[t] = excl;
    __syncthreads();
    for (int i = s + t; i < e; i += 256) {
        uint32_t p = ebuf[i];
        int slot = atomicAdd(&lcur[p >> 24], 1);
        srcs[s + slot] = (int)(p & 0x00FFFFFFu);
    }
}

// ---------------------------------------------------------------- aggregate: ax[d] = invd[d] * sum x[src[e]]
// one WAVE per dst, QUARTER-wave per edge (q=lane>>4 edge slot, cl=lane&15 uint4
// chunk): 16B/lane loads, 4 edges/step, 4 loads in flight/lane (r9 structure --
// row-major traffic-bound at ~3.6 TB/s; r12 falsified the sliced alternative).
__global__ void k_aggc(const uint4* __restrict__ x4, const int* __restrict__ rp,
                       const int* __restrict__ srcs, const float* __restrict__ invd,
                       uint4* __restrict__ axo, int N) {
    int t = threadIdx.x;
    int lane = t & 63;
    int q = lane >> 4;         // edge slot 0..3
    int cl = lane & 15;        // 16B chunk (cols cl*8 .. cl*8+7)
    int d = blockIdx.x * 4 + (t >> 6);
    if (d >= N) return;
    int s = rp[d], e = rp[d + 1];
    float a0 = 0.f, a1 = 0.f, a2 = 0.f, a3 = 0.f,
          a4 = 0.f, a5 = 0.f, a6 = 0.f, a7 = 0.f;
#define ACC8(u) { a0 += bflo(u.x); a1 += bfhi(u.x); a2 += bflo(u.y); a3 += bfhi(u.y); \
                  a4 += bflo(u.z); a5 += bfhi(u.z); a6 += bflo(u.w); a7 += bfhi(u.w); }
    for (int base = s; base < e; base += 64) {
        int m = min(64, e - base);
        int idx = (lane < m) ? srcs[base + lane] : 0;
        int j = 0;
        for (; j + 16 <= m; j += 16) {     // 16 edges: 4 uint4 loads in flight/lane
            int i0 = __shfl(idx, j + q, 64);
            int i1 = __shfl(idx, j + 4 + q, 64);
            int i2 = __shfl(idx, j + 8 + q, 64);
            int i3 = __shfl(idx, j + 12 + q, 64);
            uint4 u0 = x4[(size_t)i0 * 16 + cl];
            uint4 u1 = x4[(size_t)i1 * 16 + cl];
            uint4 u2 = x4[(size_t)i2 * 16 + cl];
            uint4 u3 = x4[(size_t)i3 * 16 + cl];
            ACC8(u0); ACC8(u1); ACC8(u2); ACC8(u3);
        }
        for (; j + 4 <= m; j += 4) {
            int id = __shfl(idx, j + q, 64);
            uint4 u = x4[(size_t)id * 16 + cl];
            ACC8(u);
        }
        if (j < m) {                       // 1..3 leftover edges
            int id = __shfl(idx, min(j + q, m - 1), 64);
            if (q < m - j) {
                uint4 u = x4[(size_t)id * 16 + cl];
                ACC8(u);
            }
        }
    }
#undef ACC8
    a0 += __shfl_down(a0, 32, 64); a1 += __shfl_down(a1, 32, 64);
    a2 += __shfl_down(a2, 32, 64); a3 += __shfl_down(a3, 32, 64);
    a4 += __shfl_down(a4, 32, 64); a5 += __shfl_down(a5, 32, 64);
    a6 += __shfl_down(a6, 32, 64); a7 += __shfl_down(a7, 32, 64);
    a0 += __shfl_down(a0, 16, 64); a1 += __shfl_down(a1, 16, 64);
    a2 += __shfl_down(a2, 16, 64); a3 += __shfl_down(a3, 16, 64);
    a4 += __shfl_down(a4, 16, 64); a5 += __shfl_down(a5, 16, 64);
    a6 += __shfl_down(a6, 16, 64); a7 += __shfl_down(a7, 16, 64);
    if (q == 0) {
        float iv = invd[d];
        uint4 o;
        o.x = pack2(a0 * iv, a1 * iv);
        o.y = pack2(a2 * iv, a3 * iv);
        o.z = pack2(a4 * iv, a5 * iv);
        o.w = pack2(a6 * iv, a7 * iv);
        axo[(size_t)d * 16 + cl] = o;
    }
}

// ---------------------------------------------------------------- dual-input bf16 MFMA GEMM (K=128 fixed):
// Xo[N,128] = relu(X @ Ws + AX @ Wn + bias_s + bias_n)   (bf16 out, fp32 acc)
// Both weights in LDS (r7: B-from-global kills MfmaUtil); A-frags for BOTH inputs
// hoisted from global (zero cross-wave reuse). Single accumulator (reorder halves
// acc registers + writes vs r9's dual-output). Epilogue LDS round-trip -> coalesced
// 16B stores.
__global__ __launch_bounds__(256, 2) void k_gemm3(
    const unsigned short* __restrict__ X, const unsigned short* __restrict__ AX,
    const unsigned short* __restrict__ Wts, const unsigned short* __restrict__ Wtn,
    int N, const float* __restrict__ bias_s, const float* __restrict__ bias_n,
    unsigned short* __restrict__ Xo) {
    __shared__ unsigned short Bs[128 * LDSPAD];   // Ws^T, 34.8 KB
    __shared__ unsigned short Bn[128 * LDSPAD];   // Wn^T, 34.8 KB
    int t = threadIdx.x;
    int rowBase = blockIdx.x << 7;

    #pragma unroll
    for (int it = 0; it < 8; it++) {
        int idx = t + it * 256;
        int n = idx >> 4, seg = idx & 15;
        *(uint4*)&Bs[n * LDSPAD + seg * 8] = *(const uint4*)(Wts + n * HIDDIM + seg * 8);
        *(uint4*)&Bn[n * LDSPAD + seg * 8] = *(const uint4*)(Wtn + n * HIDDIM + seg * 8);
    }

    int lane = t & 63;
    int wv = t >> 6;          // 4 waves -> rows [wv*32, wv*32+32)
    int ml = lane & 15;
    int quad = lane >> 4;
    int m0 = wv * 32;

    // hoisted A-frags from both inputs (16 independent uint4 loads)
    const uint4* X4 = (const uint4*)X;
    const uint4* A4 = (const uint4*)AX;
    int gr0 = rowBase + m0 + ml;
    int gr1 = gr0 + 16;
    uint4 fx0[4], fx1[4], fa0[4], fa1[4];
    #pragma unroll
    for (int kt = 0; kt < 4; kt++) {
        uint4 z = make_uint4(0u, 0u, 0u, 0u);
        size_t o0 = (size_t)gr0 * 16 + kt * 4 + quad;
        size_t o1 = (size_t)gr1 * 16 + kt * 4 + quad;
        fx0[kt] = (gr0 < N) ? X4[o0] : z;
        fx1[kt] = (gr1 < N) ? X4[o1] : z;
        fa0[kt] = (gr0 < N) ? A4[o0] : z;
        fa1[kt] = (gr1 < N) ? A4[o1] : z;
    }
    __syncthreads();

    f32x4 acc[2][8];
    #pragma unroll
    for (int i = 0; i < 2; i++)
        #pragma unroll
        for (int j = 0; j < 8; j++) acc[i][j] = (f32x4){0.f, 0.f, 0.f, 0.f};

    #pragma unroll
    for (int kt = 0; kt < 4; kt++) {
        int ko = kt * 32 + quad * 8;
        short8 x0f = *(short8*)&fx0[kt];
        short8 x1f = *(short8*)&fx1[kt];
        short8 a0f = *(short8*)&fa0[kt];
        short8 a1f = *(short8*)&fa1[kt];
        #pragma unroll
        for (int nt = 0; nt < 8; nt++) {
            short8 bs = *(const short8*)&Bs[(nt * 16 + ml) * LDSPAD + ko];
            short8 bn = *(const short8*)&Bn[(nt * 16 + ml) * LDSPAD + ko];
            acc[0][nt] = __builtin_amdgcn_mfma_f32_16x16x32_bf16(x0f, bs, acc[0][nt], 0, 0, 0);
            acc[1][nt] = __builtin_amdgcn_mfma_f32_16x16x32_bf16(x1f, bs, acc[1][nt], 0, 0, 0);
            acc[0][nt] = __builtin_amdgcn_mfma_f32_16x16x32_bf16(a0f, bn, acc[0][nt], 0, 0, 0);
            acc[1][nt] = __builtin_amdgcn_mfma_f32_16x16x32_bf16(a1f, bn, acc[1][nt], 0, 0, 0);
        }
    }

    float bsum[8];
    #pragma unroll
    for (int nt = 0; nt < 8; nt++) {
        int col = nt * 16 + ml;
        bsum[nt] = bias_s[col] + bias_n[col];
    }

    // ---- epilogue: Bs is dead; relu + LDS round-trip -> coalesced stores
    __syncthreads();
    #pragma unroll
    for (int mt = 0; mt < 2; mt++) {
        int lrow0 = m0 + mt * 16 + quad * 4;
        #pragma unroll
        for (int r = 0; r < 4; r++)
            #pragma unroll
            for (int nt = 0; nt < 8; nt++)
                Bs[(lrow0 + r) * LDSPAD + nt * 16 + ml] =
                    f2bf(fmaxf(acc[mt][nt][r] + bsum[nt], 0.f));
    }
    __syncthreads();
    #pragma unroll
    for (int it = 0; it < 8; it++) {
        int idx = t + it * 256;
        int r = idx >> 4, seg = idx & 15;
        int gr = rowBase + r;
        if (gr < N)
            *(uint4*)(Xo + (size_t)gr * HIDDIM + seg * 8) = *(const uint4*)&Bs[r * LDSPAD + seg * 8];
    }
}

// ---------------------------------------------------------------- fused mean-pool + heads (256 thr/graph)
__global__ void k_poolhead(const uint32_t* __restrict__ x, const int* __restrict__ gstart,
                           const int* __restrict__ counts,
                           const float* __restrict__ Wr, const float* __restrict__ br,
                           const float* __restrict__ Wc, const float* __restrict__ bc,
                           float* __restrict__ out, int G) {
    __shared__ float red[3][128];
    __shared__ float rowf[128];
    int gr = blockIdx.x, t = threadIdx.x;
    int wv = t >> 6, lane = t & 63;
    int half = lane >> 5, cl = lane & 31;
    int s = gstart[gr], e = gstart[gr + 1];
    const uint2* x2 = (const uint2*)x;
    float a0 = 0.f, a1 = 0.f, a2 = 0.f, a3 = 0.f;
    for (int r0 = s + wv * 2 + half; r0 < e; r0 += 32) {
        uint2 u0 = x2[(size_t)r0 * 32 + cl];
        int r1 = r0 + 8, r2 = r0 + 16, r3 = r0 + 24;
        uint2 u1 = make_uint2(0u, 0u), u2 = make_uint2(0u, 0u), u3 = make_uint2(0u, 0u);
        if (r1 < e) u1 = x2[(size_t)r1 * 32 + cl];
        if (r2 < e) u2 = x2[(size_t)r2 * 32 + cl];
        if (r3 < e) u3 = x2[(size_t)r3 * 32 + cl];
        a0 += bflo(u0.x); a1 += bfhi(u0.x); a2 += bflo(u0.y); a3 += bfhi(u0.y);
        a0 += bflo(u1.x); a1 += bfhi(u1.x); a2 += bflo(u1.y); a3 += bfhi(u1.y);
        a0 += bflo(u2.x); a1 += bfhi(u2.x); a2 += bflo(u2.y); a3 += bfhi(u2.y);
        a0 += bflo(u3.x); a1 += bfhi(u3.x); a2 += bflo(u3.y); a3 += bfhi(u3.y);
    }
    a0 += __shfl_down(a0, 32, 64);
    a1 += __shfl_down(a1, 32, 64);
    a2 += __shfl_down(a2, 32, 64);
    a3 += __shfl_down(a3, 32, 64);
    if (half == 0 && wv > 0) {
        red[wv - 1][cl * 4 + 0] = a0;
        red[wv - 1][cl * 4 + 1] = a1;
        red[wv - 1][cl * 4 + 2] = a2;
        red[wv - 1][cl * 4 + 3] = a3;
    }
    __syncthreads();
    if (wv == 0 && half == 0) {
        a0 += red[0][cl * 4 + 0] + red[1][cl * 4 + 0] + red[2][cl * 4 + 0];
        a1 += red[0][cl * 4 + 1] + red[1][cl * 4 + 1] + red[2][cl * 4 + 1];
        a2 += red[0][cl * 4 + 2] + red[1][cl * 4 + 2] + red[2][cl * 4 + 2];
        a3 += red[0][cl * 4 + 3] + red[1][cl * 4 + 3] + red[2][cl * 4 + 3];
        float inv = 1.0f / fmaxf((float)counts[gr], 1.0f);
        rowf[cl * 4 + 0] = a0 * inv;
        rowf[cl * 4 + 1] = a1 * inv;
        rowf[cl * 4 + 2] = a2 * inv;
        rowf[cl * 4 + 3] = a3 * inv;
    }
    __syncthreads();
    if (t == 0) {
        float s2 = 0.f;
        for (int k = 0; k < 128; k++) s2 += rowf[k] * Wr[k];
        out[gr] = s2 + br[0];
    } else if (t <= 10) {
        int j = t - 1;
        float s2 = 0.f;
        for (int k = 0; k < 128; k++) s2 += rowf[k] * Wc[k * 10 + j];
        out[G + gr * 10 + j] = s2 + bc[j];
    }
}

// ================================================================ host
extern "C" void kernel_launch(void* const* d_in, const int* in_sizes, int n_in,
                              void* d_out, int out_size, void* d_ws, size_t ws_size,
                              hipStream_t stream) {
    const int*   nt    = (const int*)d_in[0];
    const int*   ih    = (const int*)d_in[1];
    const float* flags = (const float*)d_in[2];
    const int*   depth = (const int*)d_in[3];
    const int*   eidx  = (const int*)d_in[4];
    const int*   batch = (const int*)d_in[5];
    const float* embN  = (const float*)d_in[6];
    const float* embI  = (const float*)d_in[7];
    const float* Ws0   = (const float*)d_in[8];
    const float* bs0   = (const float*)d_in[9];
    const float* Wn0   = (const float*)d_in[10];
    const float* bn0   = (const float*)d_in[11];
    const float* Ws1   = (const float*)d_in[12];
    const float* bs1   = (const float*)d_in[13];
    const float* Wn1   = (const float*)d_in[14];
    const float* bn1   = (const float*)d_in[15];
    const float* Wr    = (const float*)d_in[16];
    const float* br    = (const float*)d_in[17];
    const float* Wc    = (const float*)d_in[18];
    const float* bc    = (const float*)d_in[19];
    float* out = (float*)d_out;

    const int N  = in_sizes[0];
    const int E  = in_sizes[4] / 2;
    const int K0 = in_sizes[8] / HIDDIM;   // 102
    const int G  = out_size / 11;          // 512
    const int* esrc = eidx;
    const int* edst = eidx + E;
    const int NBKT = (N + 255) >> 8;       // 391

    // ---- workspace carve-up
    char* w = (char*)d_ws;
    const size_t NH = (size_t)N * HIDDIM * sizeof(unsigned short);
    unsigned short* bufA  = (unsigned short*)(w);           // x0, later x2
    unsigned short* bufB  = (unsigned short*)(w + NH);      // x1
    unsigned short* bufAX = (unsigned short*)(w + 2 * NH);  // ax (both layers)
    char* p = w + 3 * NH;
    unsigned short* Wt = (unsigned short*)p; p += (size_t)4 * HIDDIM * HIDDIM * 2;  // 128KB
    uint32_t* ebuf = (uint32_t*)p;   p += (size_t)E * 4;
    int* srcs   = (int*)p;           p += (size_t)E * 4;
    int* rowptr = (int*)p;           p += (size_t)(N + 1) * 4;
    float* invd = (float*)p;         p += (size_t)N * 4;
    int* gstart = (int*)p;           p += (size_t)(G + 1) * 4;
    int* boff   = (int*)p;           p += (size_t)(NBKT_MAX + 1) * 4;
    int* bcur   = (int*)p;           p += (size_t)NBKT_MAX * 4;
    // zeroed block: bcount, counts, maxd (contiguous)
    int* bcount = (int*)p;           p += (size_t)NBKT_MAX * 4;
    int* counts = (int*)p;           p += (size_t)G * 4;
    int* maxd   = (int*)p;           p += 4;
    const size_t zero_bytes = (size_t)(NBKT_MAX + G + 1) * 4;
    (void)n_in; (void)ws_size;

    const int nbC = (E + 4095) / 4096;               // 391
    const int nbN = (N + 255) / 256;                 // 391
    const int nbF = ((size_t)N * 16 + 255) / 256;    // 6250 (16 thr/node)
    const int nbG2 = (N + 127) / 128;
    const int nbA = (N + 3) / 4;
    const int nbD = (N + 511) / 512;

    hipMemsetAsync(bcount, 0, zero_bytes, stream);

    // fused prep: feat | bcount | nodestats | wt
    k_prep<<<nbF + nbC + nbN + 256, 256, 0, stream>>>(
        nt, ih, flags, depth, embN, embI, edst, batch,
        Wn0, Ws0, Wn1, Ws1, K0, N, E, G,
        bufA, Wt, bcount, counts, maxd, nbF, nbC, nbN);

    // fused scans + depth column
    k_scan2x<<<2 + nbD, 512, 0, stream>>>(bcount, boff, bcur, rowptr,
                                          counts, gstart, depth, maxd, bufA,
                                          NBKT, N, E, G);

    k_bscatter<<<nbC, 256, 0, stream>>>(esrc, edst, bcur, ebuf, E, NBKT);
    k_build<<<NBKT, 256, 0, stream>>>(ebuf, boff, rowptr, invd, srcs, N);

    const unsigned short* Wt_n0 = Wt;
    const unsigned short* Wt_s0 = Wt + 1 * HIDDIM * HIDDIM;
    const unsigned short* Wt_n1 = Wt + 2 * HIDDIM * HIDDIM;
    const unsigned short* Wt_s1 = Wt + 3 * HIDDIM * HIDDIM;

    // layer 0: ax = invd*(A x0) ; x1 = relu(x0@Ws0 + ax@Wn0 + b)
    k_aggc<<<nbA, 256, 0, stream>>>((const uint4*)bufA, rowptr, srcs, invd,
                                    (uint4*)bufAX, N);
    k_gemm3<<<nbG2, 256, 0, stream>>>(bufA, bufAX, Wt_s0, Wt_n0, N, bs0, bn0, bufB);

    // layer 1: ax = invd*(A x1) ; x2 = relu(x1@Ws1 + ax@Wn1 + b)  (into bufA)
    k_aggc<<<nbA, 256, 0, stream>>>((const uint4*)bufB, rowptr, srcs, invd,
                                    (uint4*)bufAX, N);
    k_gemm3<<<nbG2, 256, 0, stream>>>(bufB, bufAX, Wt_s1, Wt_n1, N, bs1, bn1, bufA);

    // fused pool + heads
    k_poolhead<<<G, 256, 0, stream>>>((const uint32_t*)bufA, gstart, counts,
                                      Wr, br, Wc, bc, out, G);
}